// Round 1
// baseline (2267.588 us; speedup 1.0000x reference)
//
#include <hip/hip_runtime.h>
#include <hip/hip_bf16.h>

#define NN 100000
#define NE 100000
#define DD 768
#define NT 5

typedef __attribute__((ext_vector_type(8))) short bf16x8;
typedef __attribute__((ext_vector_type(4))) float f32x4;
typedef __attribute__((ext_vector_type(4))) unsigned short us4;

__device__ __forceinline__ unsigned short f2bf(float f) {
    unsigned int u = __builtin_bit_cast(unsigned int, f);
    u = (u + 0x7FFFu + ((u >> 16) & 1u)) >> 16;
    return (unsigned short)u;
}

// meta layout (ints): [0..4]=cnt, [8..13]=bucketStart(excl scan,6), [16..20]=cursor,
// [24..28]=nETiles, [32..37]=blockStart(6)

__global__ void k_convw(const float* __restrict__ Wm, const float* __restrict__ Wu,
                        unsigned short* __restrict__ dst) {
    const int nm = 5 * 768 * 768 / 4, nu = 768 * 1536 / 4, n = nm + nu;
    for (int i = blockIdx.x * blockDim.x + threadIdx.x; i < n; i += gridDim.x * blockDim.x) {
        float4 v = (i < nm) ? ((const float4*)Wm)[i] : ((const float4*)Wu)[i - nm];
        us4 o = {f2bf(v.x), f2bf(v.y), f2bf(v.z), f2bf(v.w)};
        ((us4*)dst)[i] = o;
    }
}

__global__ void k_hist(const int* __restrict__ et, int* __restrict__ meta) {
    __shared__ int lc[NT];
    if (threadIdx.x < NT) lc[threadIdx.x] = 0;
    __syncthreads();
    for (int e = blockIdx.x * blockDim.x + threadIdx.x; e < NE; e += gridDim.x * blockDim.x)
        atomicAdd(&lc[et[e]], 1);
    __syncthreads();
    if (threadIdx.x < NT && lc[threadIdx.x]) atomicAdd(&meta[threadIdx.x], lc[threadIdx.x]);
}

__global__ void k_scan(int* __restrict__ meta) {
    meta[8] = 0;
    for (int t = 0; t < NT; t++) {
        int c = meta[t];
        meta[8 + t + 1] = meta[8 + t] + c;
        meta[16 + t] = meta[8 + t];
        meta[24 + t] = (c + 63) >> 6;
    }
    meta[32] = 0;
    for (int t = 0; t < NT; t++) meta[32 + t + 1] = meta[32 + t] + meta[24 + t] * 3;
}

__global__ void k_fill(const int* __restrict__ et, int* __restrict__ meta, int* __restrict__ perm) {
    __shared__ int lc[NT], gb[NT];
    if (threadIdx.x < NT) lc[threadIdx.x] = 0;
    __syncthreads();
    int e = blockIdx.x * blockDim.x + threadIdx.x;
    int t = 0, r = 0;
    if (e < NE) { t = et[e]; r = atomicAdd(&lc[t], 1); }
    __syncthreads();
    if (threadIdx.x < NT) {
        int c = lc[threadIdx.x];
        gb[threadIdx.x] = c ? atomicAdd(&meta[16 + threadIdx.x], c) : 0;
    }
    __syncthreads();
    if (e < NE) perm[gb[t] + r] = e;
}

// Stage A: per-type GEMM of gathered src features vs W_msg[t]^T, atomic scatter into agg.
// Tile: 64 edges x 256 out-cols, K=768 in chunks of 64. 256 threads (4 waves).
__launch_bounds__(256)
__global__ void k_msg(const float* __restrict__ x, const unsigned short* __restrict__ WmsgB,
                      const float* __restrict__ bmsg, const int* __restrict__ esrc,
                      const int* __restrict__ etgt, const int* __restrict__ perm,
                      const int* __restrict__ meta, float* agg) {
    __shared__ unsigned short Xs[64][72];
    __shared__ unsigned short Ws[256][72];
    __shared__ int e_src[64], e_tgt[64];

    int b = blockIdx.x;
    if (b >= meta[32 + 5]) return;
    int t = 0;
    while (t < NT - 1 && b >= meta[32 + t + 1]) t++;
    int local = b - meta[32 + t];
    int ne = meta[24 + t];
    int etile = local % ne, ctile = local / ne;
    int ebase = meta[8 + t] + (etile << 6);
    int ecnt = meta[8 + t + 1] - ebase;
    if (ecnt > 64) ecnt = 64;

    int tid = threadIdx.x;
    if (tid < 64) {
        int s = 0, g = 0;
        if (tid < ecnt) { int e = perm[ebase + tid]; s = esrc[e]; g = etgt[e]; }
        e_src[tid] = s; e_tgt[tid] = g;
    }
    __syncthreads();

    int lane = tid & 63, wid = tid >> 6;
    f32x4 acc[4][4];
    #pragma unroll
    for (int m = 0; m < 4; m++)
        #pragma unroll
        for (int n = 0; n < 4; n++) acc[m][n] = (f32x4){0.f, 0.f, 0.f, 0.f};

    int row = tid >> 2, q = tid & 3;
    const unsigned short* wrow = WmsgB + (size_t)t * 768 * 768 + ((size_t)((ctile << 8) + tid)) * 768;
    int nbase = wid << 6;

    for (int kc = 0; kc < 768; kc += 64) {
        const float* xr = x + (size_t)e_src[row] * 768 + kc + (q << 4);
        #pragma unroll
        for (int j = 0; j < 4; j++) {
            float4 v = ((const float4*)xr)[j];
            us4 o = {f2bf(v.x), f2bf(v.y), f2bf(v.z), f2bf(v.w)};
            *(us4*)&Xs[row][(q << 4) + (j << 2)] = o;
        }
        #pragma unroll
        for (int j = 0; j < 8; j++) {
            uint4 v = ((const uint4*)(wrow + kc))[j];
            *(uint4*)&Ws[tid][j << 3] = v;
        }
        __syncthreads();
        #pragma unroll
        for (int ks = 0; ks < 64; ks += 32) {
            bf16x8 a[4];
            #pragma unroll
            for (int m = 0; m < 4; m++)
                a[m] = *(const bf16x8*)&Xs[(m << 4) + (lane & 15)][ks + ((lane >> 4) << 3)];
            #pragma unroll
            for (int n = 0; n < 4; n++) {
                bf16x8 bf = *(const bf16x8*)&Ws[nbase + (n << 4) + (lane & 15)][ks + ((lane >> 4) << 3)];
                #pragma unroll
                for (int m = 0; m < 4; m++)
                    acc[m][n] = __builtin_amdgcn_mfma_f32_16x16x32_bf16(a[m], bf, acc[m][n], 0, 0, 0);
            }
        }
        __syncthreads();
    }

    #pragma unroll
    for (int m = 0; m < 4; m++) {
        #pragma unroll
        for (int i = 0; i < 4; i++) {
            int r = (m << 4) + ((lane >> 4) << 2) + i;
            if (r < ecnt) {
                int tg = e_tgt[r];
                #pragma unroll
                for (int n = 0; n < 4; n++) {
                    int col = (ctile << 8) + nbase + (n << 4) + (lane & 15);
                    float v = acc[m][n][i] + bmsg[t * 768 + col];
                    unsafeAtomicAdd(&agg[(size_t)tg * 768 + col], v);
                }
            }
        }
    }
}

// Stage B: out = LN(x + relu(concat(x,agg) @ Wupd^T + b)). Tile 64 rows x 768 cols,
// 512 threads (8 waves: 4 row-groups x 2 col-groups). In-place over d_out (agg rows
// of this block only are read, all reads precede the epilogue writes).
__launch_bounds__(512)
__global__ void k_upd(const float* __restrict__ x, const float* agg,
                      const unsigned short* __restrict__ WupdB, const float* __restrict__ bupd,
                      const float* __restrict__ gamma, const float* __restrict__ beta,
                      float* out) {
    __shared__ unsigned short Xs[64][40];
    __shared__ unsigned short Ws[768][40];
    __shared__ float red[64][2][2];

    int tid = threadIdx.x, lane = tid & 63, wid = tid >> 6;
    int wm = wid >> 1, wn = wid & 1;
    int rbase = blockIdx.x << 6;

    f32x4 acc[24];
    #pragma unroll
    for (int n = 0; n < 24; n++) acc[n] = (f32x4){0.f, 0.f, 0.f, 0.f};

    int srow = tid >> 3, sq = tid & 7;
    int grow_s = rbase + srow;
    if (grow_s >= NN) grow_s = NN - 1;

    for (int kc = 0; kc < 1536; kc += 32) {
        const float* src = (kc < 768) ? (x + (size_t)grow_s * 768 + kc)
                                      : (agg + (size_t)grow_s * 768 + (kc - 768));
        float4 v = *(const float4*)(src + (sq << 2));
        us4 o = {f2bf(v.x), f2bf(v.y), f2bf(v.z), f2bf(v.w)};
        *(us4*)&Xs[srow][sq << 2] = o;
        {
            const unsigned short* wr = WupdB + (size_t)tid * 1536 + kc;
            #pragma unroll
            for (int j = 0; j < 4; j++) *(uint4*)&Ws[tid][j << 3] = ((const uint4*)wr)[j];
            if (tid < 256) {
                const unsigned short* wr2 = WupdB + (size_t)(tid + 512) * 1536 + kc;
                #pragma unroll
                for (int j = 0; j < 4; j++) *(uint4*)&Ws[tid + 512][j << 3] = ((const uint4*)wr2)[j];
            }
        }
        __syncthreads();
        bf16x8 a = *(const bf16x8*)&Xs[(wm << 4) + (lane & 15)][(lane >> 4) << 3];
        #pragma unroll
        for (int n = 0; n < 24; n++) {
            bf16x8 bfr = *(const bf16x8*)&Ws[wn * 384 + (n << 4) + (lane & 15)][(lane >> 4) << 3];
            acc[n] = __builtin_amdgcn_mfma_f32_16x16x32_bf16(a, bfr, acc[n], 0, 0, 0);
        }
        __syncthreads();
    }

    int rl = (lane >> 4) << 2;
    float p[4] = {0, 0, 0, 0}, qq[4] = {0, 0, 0, 0};
    #pragma unroll
    for (int i = 0; i < 4; i++) {
        int grow = rbase + (wm << 4) + rl + i;
        int gr = grow < NN ? grow : NN - 1;
        #pragma unroll
        for (int n = 0; n < 24; n++) {
            int col = wn * 384 + (n << 4) + (lane & 15);
            float u = acc[n][i] + bupd[col];
            u = u > 0.f ? u : 0.f;
            float v = u + x[(size_t)gr * 768 + col];
            acc[n][i] = v;
            p[i] += v; qq[i] += v * v;
        }
    }
    #pragma unroll
    for (int i = 0; i < 4; i++) {
        #pragma unroll
        for (int m = 1; m < 16; m <<= 1) {
            p[i] += __shfl_xor(p[i], m, 64);
            qq[i] += __shfl_xor(qq[i], m, 64);
        }
    }
    if ((lane & 15) == 0) {
        #pragma unroll
        for (int i = 0; i < 4; i++) {
            int r = (wm << 4) + rl + i;
            red[r][wn][0] = p[i];
            red[r][wn][1] = qq[i];
        }
    }
    __syncthreads();
    #pragma unroll
    for (int i = 0; i < 4; i++) {
        int r = (wm << 4) + rl + i;
        int grow = rbase + r;
        if (grow < NN) {
            float s = red[r][0][0] + red[r][1][0];
            float ss = red[r][0][1] + red[r][1][1];
            float mu = s * (1.f / 768.f);
            float var = ss * (1.f / 768.f) - mu * mu;
            float rs = rsqrtf(var + 1e-5f);
            #pragma unroll
            for (int n = 0; n < 24; n++) {
                int col = wn * 384 + (n << 4) + (lane & 15);
                out[(size_t)grow * 768 + col] = (acc[n][i] - mu) * rs * gamma[col] + beta[col];
            }
        }
    }
}

extern "C" void kernel_launch(void* const* d_in, const int* in_sizes, int n_in,
                              void* d_out, int out_size, void* d_ws, size_t ws_size,
                              hipStream_t stream) {
    const float* x     = (const float*)d_in[0];
    const float* Wmsg  = (const float*)d_in[1];
    const float* bmsg  = (const float*)d_in[2];
    const float* Wupd  = (const float*)d_in[3];
    const float* bupd  = (const float*)d_in[4];
    const float* gamma = (const float*)d_in[5];
    const float* beta  = (const float*)d_in[6];
    const int* eidx    = (const int*)d_in[7];
    const int* etype   = (const int*)d_in[8];
    const int* esrc = eidx;
    const int* etgt = eidx + NE;

    unsigned short* WmsgB = (unsigned short*)d_ws;
    unsigned short* WupdB = WmsgB + 5 * 768 * 768;
    int* perm = (int*)(WupdB + 768 * 1536);
    int* meta = perm + NE;
    float* outp = (float*)d_out;

    hipMemsetAsync(d_out, 0, (size_t)NN * DD * sizeof(float), stream);
    hipMemsetAsync(meta, 0, 64 * sizeof(int), stream);
    hipLaunchKernelGGL(k_convw, dim3(2048), dim3(256), 0, stream, Wmsg, Wupd, WmsgB);
    hipLaunchKernelGGL(k_hist, dim3(256), dim3(256), 0, stream, etype, meta);
    hipLaunchKernelGGL(k_scan, dim3(1), dim3(1), 0, stream, meta);
    hipLaunchKernelGGL(k_fill, dim3((NE + 255) / 256), dim3(256), 0, stream, etype, meta, perm);
    hipLaunchKernelGGL(k_msg, dim3(4704), dim3(256), 0, stream, x, WmsgB, bmsg, esrc, etgt, perm, meta, outp);
    hipLaunchKernelGGL(k_upd, dim3((NN + 63) / 64), dim3(512), 0, stream, x, outp, WupdB, bupd, gamma, beta, outp);
}

// Round 2
// 1849.568 us; speedup vs baseline: 1.2260x; 1.2260x over previous
//
#include <hip/hip_runtime.h>
#include <hip/hip_bf16.h>

#define NN 100000
#define NE 100000
#define NT 5

typedef __attribute__((ext_vector_type(8))) short bf16x8;
typedef __attribute__((ext_vector_type(4))) float f32x4;
typedef __attribute__((ext_vector_type(4))) unsigned short us4;

__device__ __forceinline__ unsigned short f2bf(float f) {
    unsigned int u = __builtin_bit_cast(unsigned int, f);
    u = (u + 0x7FFFu + ((u >> 16) & 1u)) >> 16;
    return (unsigned short)u;
}

// async global->LDS, 16B per lane, linear LDS dest (wave base + lane*16)
#define GLDS16(g, l) __builtin_amdgcn_global_load_lds( \
    (const __attribute__((address_space(1))) unsigned int*)(g), \
    (__attribute__((address_space(3))) unsigned int*)(l), 16, 0, 0)

#define BAR() do { asm volatile("" ::: "memory"); __builtin_amdgcn_s_barrier(); asm volatile("" ::: "memory"); } while (0)

// ---------------------------------------------------------------------------
// Weight pre-pack. Chunk-contiguous layout so staging is a linear 16B-granule
// copy (global_load_lds-friendly), with the k-slot XOR baked into the SOURCE
// so the swizzled ds_read on the consume side lands on the right data
// (both-sides-or-neither rule).
//   WmP[t][ch 0..23][n 0..767][s 0..3] : 8 bf16 = Wm[t][n][ch*32 + (s^((n>>1)&3))*8 ..+7]
//   WuP[ch 0..47][n 0..767][s 0..3]    : 8 bf16 = Wu[n][ch*32 + (s^((n>>1)&3))*8 ..+7]
// ---------------------------------------------------------------------------
__global__ void k_pack(const float* __restrict__ Wm, const float* __restrict__ Wu,
                       unsigned short* __restrict__ WmP, unsigned short* __restrict__ WuP) {
    const int NM = 5 * 24 * 768 * 4, NU = 48 * 768 * 4;
    for (int i = blockIdx.x * blockDim.x + threadIdx.x; i < NM + NU;
         i += gridDim.x * blockDim.x) {
        const float* src;
        unsigned short* dst;
        if (i < NM) {
            int t = i / (24 * 768 * 4), r = i % (24 * 768 * 4);
            int ch = r / 3072, r2 = r % 3072, n = r2 >> 2, s = r2 & 3;
            src = Wm + ((size_t)t * 768 + n) * 768 + (ch << 5) + ((s ^ ((n >> 1) & 3)) << 3);
            dst = WmP + (size_t)i * 8;
        } else {
            int j = i - NM;
            int ch = j / 3072, r2 = j % 3072, n = r2 >> 2, s = r2 & 3;
            src = Wu + (size_t)n * 1536 + (ch << 5) + ((s ^ ((n >> 1) & 3)) << 3);
            dst = WuP + (size_t)j * 8;
        }
        float4 a = ((const float4*)src)[0], b = ((const float4*)src)[1];
        us4 o0 = {f2bf(a.x), f2bf(a.y), f2bf(a.z), f2bf(a.w)};
        us4 o1 = {f2bf(b.x), f2bf(b.y), f2bf(b.z), f2bf(b.w)};
        ((us4*)dst)[0] = o0;
        ((us4*)dst)[1] = o1;
    }
}

// meta: [0..4]=cnt [8..13]=bucketStart [16..20]=cursor [24..28]=nETiles [32..37]=blockStart
__global__ void k_hist(const int* __restrict__ et, int* __restrict__ meta) {
    __shared__ int lc[NT];
    if (threadIdx.x < NT) lc[threadIdx.x] = 0;
    __syncthreads();
    for (int e = blockIdx.x * blockDim.x + threadIdx.x; e < NE; e += gridDim.x * blockDim.x)
        atomicAdd(&lc[et[e]], 1);
    __syncthreads();
    if (threadIdx.x < NT && lc[threadIdx.x]) atomicAdd(&meta[threadIdx.x], lc[threadIdx.x]);
}

__global__ void k_scan(int* __restrict__ meta) {
    meta[8] = 0;
    for (int t = 0; t < NT; t++) {
        int c = meta[t];
        meta[8 + t + 1] = meta[8 + t] + c;
        meta[16 + t] = meta[8 + t];
        meta[24 + t] = (c + 63) >> 6;
    }
    meta[32] = 0;
    for (int t = 0; t < NT; t++) meta[32 + t + 1] = meta[32 + t] + meta[24 + t];
}

__global__ void k_fill(const int* __restrict__ et, int* __restrict__ meta, int* __restrict__ perm) {
    __shared__ int lc[NT], gb[NT];
    if (threadIdx.x < NT) lc[threadIdx.x] = 0;
    __syncthreads();
    int e = blockIdx.x * blockDim.x + threadIdx.x;
    int t = 0, r = 0;
    if (e < NE) { t = et[e]; r = atomicAdd(&lc[t], 1); }
    __syncthreads();
    if (threadIdx.x < NT) {
        int c = lc[threadIdx.x];
        gb[threadIdx.x] = c ? atomicAdd(&meta[16 + threadIdx.x], c) : 0;
    }
    __syncthreads();
    if (e < NE) perm[gb[t] + r] = e;
}

// ---------------------------------------------------------------------------
// Stage A: 64 edges x 768 cols per block. 8 waves = 4 edge-groups x 2 col-halves.
// K=768 in 24 chunks of 32, double-buffered LDS, counted vmcnt (7 loads/stage).
// Epilogue: +bias, atomic scatter to agg rows.
// ---------------------------------------------------------------------------
__launch_bounds__(512, 2)
__global__ void k_msg(const float* __restrict__ x, const unsigned short* __restrict__ WmP,
                      const float* __restrict__ bmsg, const int* __restrict__ esrc,
                      const int* __restrict__ etgt, const int* __restrict__ perm,
                      const int* __restrict__ meta, float* agg) {
    __shared__ __align__(16) unsigned short Ws[2][768 * 32];  // 48KB x2
    __shared__ __align__(16) float Xs[2][64 * 32];            // 8KB x2
    __shared__ int e_src[64], e_tgt[64];

    int b = blockIdx.x;
    if (b >= meta[37]) return;
    int t = 0;
    while (t < NT - 1 && b >= meta[32 + t + 1]) t++;
    int etile = b - meta[32 + t];
    int ebase = meta[8 + t] + (etile << 6);
    int ecnt = meta[8 + t + 1] - ebase;
    if (ecnt > 64) ecnt = 64;

    int tid = threadIdx.x;
    if (tid < 64) {
        int s = 0, g = 0;
        if (tid < ecnt) { int e = perm[ebase + tid]; s = esrc[e]; g = etgt[e]; }
        e_src[tid] = s; e_tgt[tid] = g;
    }
    __syncthreads();

    int lane = tid & 63, wid = tid >> 6;
    int wm = wid >> 1, wn = wid & 1;
    unsigned wave_base = tid & ~63u;

    // Xs staging: granule G = tid (row = G>>3, slot s = G&7); source k-slot XOR'd by row&7.
    int srow = tid >> 3, sslot = tid & 7;
    const float* xsrc_row = x + (size_t)e_src[srow] * 768 + ((sslot ^ (srow & 7)) << 2);
    const unsigned short* wbase = WmP + (size_t)t * (24 * 768 * 32);

    f32x4 acc[24];
    #pragma unroll
    for (int n = 0; n < 24; n++) acc[n] = (f32x4){0.f, 0.f, 0.f, 0.f};

    auto stage = [&](int p, int ch) {
        const unsigned short* wsrc = wbase + (size_t)ch * 24576;
        #pragma unroll
        for (int j = 0; j < 6; j++)
            GLDS16(wsrc + ((j * 512 + tid) << 3), &Ws[p][(j * 512 + wave_base) << 3]);
        GLDS16(xsrc_row + (ch << 5), &Xs[p][wave_base << 2]);
    };

    int g = lane >> 4;
    int ar = (wm << 4) + (lane & 15);
    int xoff0 = ar * 32 + ((((g << 1) + 0) ^ (ar & 7)) << 2);
    int xoff1 = ar * 32 + ((((g << 1) + 1) ^ (ar & 7)) << 2);
    int cn0 = wn * 384 + (lane & 15);

    stage(0, 0);
    #pragma unroll 2
    for (int ch = 0; ch < 24; ch++) {
        int p = ch & 1;
        if (ch + 1 < 24) {
            stage(p ^ 1, ch + 1);
            asm volatile("s_waitcnt vmcnt(7)" ::: "memory");
        } else {
            asm volatile("s_waitcnt vmcnt(0)" ::: "memory");
        }
        BAR();
        f32x4 fa0 = *(const f32x4*)&Xs[p][xoff0];
        f32x4 fa1 = *(const f32x4*)&Xs[p][xoff1];
        bf16x8 a;
        a[0] = (short)f2bf(fa0[0]); a[1] = (short)f2bf(fa0[1]);
        a[2] = (short)f2bf(fa0[2]); a[3] = (short)f2bf(fa0[3]);
        a[4] = (short)f2bf(fa1[0]); a[5] = (short)f2bf(fa1[1]);
        a[6] = (short)f2bf(fa1[2]); a[7] = (short)f2bf(fa1[3]);
        #pragma unroll
        for (int nf = 0; nf < 24; nf++) {
            int n = cn0 + (nf << 4);
            bf16x8 bb = *(const bf16x8*)&Ws[p][(n << 5) + ((g ^ ((n >> 1) & 3)) << 3)];
            acc[nf] = __builtin_amdgcn_mfma_f32_16x16x32_bf16(a, bb, acc[nf], 0, 0, 0);
        }
        BAR();
    }

    const float* bms = bmsg + t * 768;
    int g4 = (lane >> 4) << 2;
    #pragma unroll
    for (int i = 0; i < 4; i++) {
        int r = (wm << 4) + g4 + i;
        bool ok = r < ecnt;
        int tg = e_tgt[r];
        #pragma unroll
        for (int nf = 0; nf < 24; nf++) {
            int col = cn0 + (nf << 4);
            float v = acc[nf][i] + bms[col];
            if (ok) unsafeAtomicAdd(&agg[(size_t)tg * 768 + col], v);
        }
    }
}

// ---------------------------------------------------------------------------
// Stage B: 128 rows x 768 cols per block. 8 waves = 4 row-groups(32) x 2 col-halves(384).
// K=1536 in 48 chunks of 32 (first 24 from x, last 24 from agg), double-buffered,
// counted vmcnt (8 loads/stage). Fused bias+ReLU+residual+LayerNorm epilogue.
// In-place: agg == out; block reads only its own rows, writes after all reads.
// ---------------------------------------------------------------------------
__launch_bounds__(512, 2)
__global__ void k_upd(const float* __restrict__ x, const float* agg,
                      const unsigned short* __restrict__ WuP, const float* __restrict__ bupd,
                      const float* __restrict__ gamma, const float* __restrict__ beta,
                      float* out) {
    __shared__ __align__(16) unsigned short Ws[2][768 * 32];  // 48KB x2
    __shared__ __align__(16) float Xs[2][128 * 32];           // 16KB x2
    __shared__ float red[128][4];

    int tid = threadIdx.x, lane = tid & 63, wid = tid >> 6;
    int wm = wid >> 1, wn = wid & 1;
    int rbase = blockIdx.x << 7;
    unsigned wave_base = tid & ~63u;

    // Xs staging: 1024 granules; thread covers G=tid and G=tid+512.
    int r0 = tid >> 3, s0 = tid & 7;
    int r1 = (tid + 512) >> 3;
    int rg0 = rbase + r0; if (rg0 >= NN) rg0 = NN - 1;
    int rg1 = rbase + r1; if (rg1 >= NN) rg1 = NN - 1;
    size_t xo0 = (size_t)rg0 * 768 + ((s0 ^ (r0 & 7)) << 2);
    size_t xo1 = (size_t)rg1 * 768 + ((s0 ^ (r1 & 7)) << 2);

    f32x4 acc[2][24];
    #pragma unroll
    for (int m = 0; m < 2; m++)
        #pragma unroll
        for (int n = 0; n < 24; n++) acc[m][n] = (f32x4){0.f, 0.f, 0.f, 0.f};

    auto stage = [&](int p, int ch) {
        const unsigned short* wsrc = WuP + (size_t)ch * 24576;
        #pragma unroll
        for (int j = 0; j < 6; j++)
            GLDS16(wsrc + ((j * 512 + tid) << 3), &Ws[p][(j * 512 + wave_base) << 3]);
        int kc = ch << 5;
        const float* f0 = (kc < 768) ? (x + xo0 + kc) : (agg + xo0 + (kc - 768));
        const float* f1 = (kc < 768) ? (x + xo1 + kc) : (agg + xo1 + (kc - 768));
        GLDS16(f0, &Xs[p][wave_base << 2]);
        GLDS16(f1, &Xs[p][(512 + wave_base) << 2]);
    };

    int g = lane >> 4;
    int ar0 = (wm << 5) + (lane & 15);
    int xoffA[2][2];
    #pragma unroll
    for (int m = 0; m < 2; m++) {
        int ar = ar0 + (m << 4);
        xoffA[m][0] = ar * 32 + ((((g << 1) + 0) ^ (ar & 7)) << 2);
        xoffA[m][1] = ar * 32 + ((((g << 1) + 1) ^ (ar & 7)) << 2);
    }
    int cn0 = wn * 384 + (lane & 15);

    stage(0, 0);
    #pragma unroll 2
    for (int ch = 0; ch < 48; ch++) {
        int p = ch & 1;
        if (ch + 1 < 48) {
            stage(p ^ 1, ch + 1);
            asm volatile("s_waitcnt vmcnt(8)" ::: "memory");
        } else {
            asm volatile("s_waitcnt vmcnt(0)" ::: "memory");
        }
        BAR();
        bf16x8 a0, a1;
        {
            f32x4 f00 = *(const f32x4*)&Xs[p][xoffA[0][0]];
            f32x4 f01 = *(const f32x4*)&Xs[p][xoffA[0][1]];
            f32x4 f10 = *(const f32x4*)&Xs[p][xoffA[1][0]];
            f32x4 f11 = *(const f32x4*)&Xs[p][xoffA[1][1]];
            a0[0] = (short)f2bf(f00[0]); a0[1] = (short)f2bf(f00[1]);
            a0[2] = (short)f2bf(f00[2]); a0[3] = (short)f2bf(f00[3]);
            a0[4] = (short)f2bf(f01[0]); a0[5] = (short)f2bf(f01[1]);
            a0[6] = (short)f2bf(f01[2]); a0[7] = (short)f2bf(f01[3]);
            a1[0] = (short)f2bf(f10[0]); a1[1] = (short)f2bf(f10[1]);
            a1[2] = (short)f2bf(f10[2]); a1[3] = (short)f2bf(f10[3]);
            a1[4] = (short)f2bf(f11[0]); a1[5] = (short)f2bf(f11[1]);
            a1[6] = (short)f2bf(f11[2]); a1[7] = (short)f2bf(f11[3]);
        }
        #pragma unroll
        for (int nf = 0; nf < 24; nf++) {
            int n = cn0 + (nf << 4);
            bf16x8 bb = *(const bf16x8*)&Ws[p][(n << 5) + ((g ^ ((n >> 1) & 3)) << 3)];
            acc[0][nf] = __builtin_amdgcn_mfma_f32_16x16x32_bf16(a0, bb, acc[0][nf], 0, 0, 0);
            acc[1][nf] = __builtin_amdgcn_mfma_f32_16x16x32_bf16(a1, bb, acc[1][nf], 0, 0, 0);
        }
        BAR();
    }

    // epilogue: bias + relu + residual, row sums, LN, store
    int g4 = (lane >> 4) << 2;
    #pragma unroll
    for (int m = 0; m < 2; m++) {
        #pragma unroll
        for (int i = 0; i < 4; i++) {
            int r = (wm << 5) + (m << 4) + g4 + i;
            int grow = rbase + r;
            int gr = grow < NN ? grow : NN - 1;
            const float* xr = x + (size_t)gr * 768;
            float a_ = 0.f, b_ = 0.f;
            #pragma unroll
            for (int nf = 0; nf < 24; nf++) {
                int col = cn0 + (nf << 4);
                float u = acc[m][nf][i] + bupd[col];
                u = u > 0.f ? u : 0.f;
                float v = u + xr[col];
                acc[m][nf][i] = v;
                a_ += v; b_ += v * v;
            }
            #pragma unroll
            for (int d = 1; d < 16; d <<= 1) {
                a_ += __shfl_xor(a_, d, 64);
                b_ += __shfl_xor(b_, d, 64);
            }
            if ((lane & 15) == 0) { red[r][wn * 2] = a_; red[r][wn * 2 + 1] = b_; }
        }
    }
    __syncthreads();
    #pragma unroll
    for (int m = 0; m < 2; m++) {
        #pragma unroll
        for (int i = 0; i < 4; i++) {
            int r = (wm << 5) + (m << 4) + g4 + i;
            int grow = rbase + r;
            if (grow < NN) {
                float s = red[r][0] + red[r][2];
                float ss = red[r][1] + red[r][3];
                float mu = s * (1.f / 768.f);
                float var = ss * (1.f / 768.f) - mu * mu;
                float rs = rsqrtf(var + 1e-5f);
                float* orow = out + (size_t)grow * 768;
                #pragma unroll
                for (int nf = 0; nf < 24; nf++) {
                    int col = cn0 + (nf << 4);
                    orow[col] = (acc[m][nf][i] - mu) * rs * gamma[col] + beta[col];
                }
            }
        }
    }
}

extern "C" void kernel_launch(void* const* d_in, const int* in_sizes, int n_in,
                              void* d_out, int out_size, void* d_ws, size_t ws_size,
                              hipStream_t stream) {
    const float* x     = (const float*)d_in[0];
    const float* Wmsg  = (const float*)d_in[1];
    const float* bmsg  = (const float*)d_in[2];
    const float* Wupd  = (const float*)d_in[3];
    const float* bupd  = (const float*)d_in[4];
    const float* gamma = (const float*)d_in[5];
    const float* beta  = (const float*)d_in[6];
    const int* eidx    = (const int*)d_in[7];
    const int* etype   = (const int*)d_in[8];
    const int* esrc = eidx;
    const int* etgt = eidx + NE;

    unsigned short* WmP = (unsigned short*)d_ws;                 // 5*24*768*4*8 bf16
    unsigned short* WuP = WmP + (size_t)5 * 24 * 768 * 32;       // 48*768*4*8 bf16
    int* perm = (int*)(WuP + (size_t)48 * 768 * 32);
    int* meta = perm + NE;
    float* outp = (float*)d_out;

    hipMemsetAsync(d_out, 0, (size_t)NN * 768 * sizeof(float), stream);
    hipMemsetAsync(meta, 0, 64 * sizeof(int), stream);
    hipLaunchKernelGGL(k_pack, dim3(1024), dim3(256), 0, stream, Wmsg, Wupd, WmP, WuP);
    hipLaunchKernelGGL(k_hist, dim3(256), dim3(256), 0, stream, etype, meta);
    hipLaunchKernelGGL(k_scan, dim3(1), dim3(1), 0, stream, meta);
    hipLaunchKernelGGL(k_fill, dim3((NE + 255) / 256), dim3(256), 0, stream, etype, meta, perm);
    hipLaunchKernelGGL(k_msg, dim3(1568), dim3(512), 0, stream, x, WmP, bmsg, esrc, etgt, perm, meta, outp);
    hipLaunchKernelGGL(k_upd, dim3((NN + 127) / 128), dim3(512), 0, stream, x, outp, WuP, bupd, gamma, beta, outp);
}